// Round 25
// baseline (69.832 us; speedup 1.0000x reference)
//
#include <hip/hip_runtime.h>

typedef float  f32x4  __attribute__((ext_vector_type(4)));
typedef short  short8 __attribute__((ext_vector_type(8)));
typedef short  short4_ __attribute__((ext_vector_type(4)));

constexpr int Bb = 8, T = 2048, D = 768, HS = 64;
constexpr int BT = Bb * T;
constexpr int QT = T / 64;              // 32 q-tiles per batch
constexpr int PSTRIDE = 64 * 64 + 128;  // floats per partial (O' + m + l)

__device__ __forceinline__ short f2bf(float f) {
    unsigned u = __builtin_bit_cast(unsigned, f);
    unsigned r = (u + 0x7FFFu + ((u >> 16) & 1u)) >> 16;
    return (short)r;
}

__device__ __forceinline__ void gld_lds16(const void* g, void* l) {
    __builtin_amdgcn_global_load_lds(
        (const __attribute__((address_space(1))) unsigned int*)g,
        (__attribute__((address_space(3))) unsigned int*)l, 16, 0, 0);
}

// ---------------------------------------------------------------------------
// Kernel 0: transpose Wq|Wk|Wv (fp32 [768][64] each) -> Wt bf16 [192][768]
// ---------------------------------------------------------------------------
__global__ __launch_bounds__(256) void wt_kernel(const float* __restrict__ Wq,
                                                 const float* __restrict__ Wk,
                                                 const float* __restrict__ Wv,
                                                 short* __restrict__ Wt) {
    int n = blockIdx.x;                       // 0..191 composite output col
    const float* W = (n < 64) ? Wq : (n < 128) ? Wk : Wv;
    int c = n & 63;
    for (int kk = threadIdx.x; kk < D; kk += 256)
        Wt[n * D + kk] = f2bf(W[kk * HS + c]);
}

// ---------------------------------------------------------------------------
// Kernel 1: QKV projection (R14 pipelined structure, ~11.5 us measured R16).
// q pre-scaled by 1/8 (R20 exact).
// ---------------------------------------------------------------------------
__global__ __launch_bounds__(512) void qkv_proj(const float* __restrict__ x,
                                                const short* __restrict__ Wt,
                                                short* __restrict__ qws,
                                                short* __restrict__ kws,
                                                short* __restrict__ vtg) {
    __shared__ alignas(16) short wtile[3][192 * 64]; // 72 KB bf16
    __shared__ alignas(16) float xls[3][64 * 64];    // 48 KB fp32

    const int tid  = threadIdx.x;             // 0..511
    const int lane = tid & 63, w = tid >> 6;
    const int lo   = lane & 15, hi = lane >> 4;
    const int wr   = w >> 2, wc = w & 3;      // wave row (2) x col (4)
    const int row0 = blockIdx.x * 64;
    const int b    = row0 >> 11, t0 = row0 & 2047;

    f32x4 acc[6];
#pragma unroll
    for (int j = 0; j < 6; j++) acc[j] = f32x4{0.f, 0.f, 0.f, 0.f};

#define STAGE_W(bufi, kc)                                                      \
    {                                                                          \
        _Pragma("unroll")                                                      \
        for (int it = 0; it < 3; it++) {                                       \
            int ci = it * 512 + w * 64 + lane;                                 \
            int n = ci >> 3, seg = ci & 7;                                     \
            gld_lds16(&Wt[(size_t)n * D + (kc) * 64 + ((seg ^ (n & 7)) << 3)], \
                      &wtile[bufi][(it * 512 + w * 64) * 8]);                  \
        }                                                                      \
    }
#define STAGE_X(bufi, kc)                                                      \
    {                                                                          \
        _Pragma("unroll")                                                      \
        for (int it = 0; it < 2; it++) {                                       \
            int idx = it * 512 + tid;                                          \
            int row = idx >> 4, g = idx & 15;                                  \
            int sg = (g & 8) | ((g & 7) ^ (row & 7));                          \
            gld_lds16(&x[(size_t)(row0 + row) * D + (kc) * 64 + sg * 4],       \
                      &xls[bufi][(it * 512 + w * 64) * 4]);                    \
        }                                                                      \
    }

    STAGE_W(0, 0); STAGE_X(0, 0);
    STAGE_W(1, 1); STAGE_X(1, 1);
    STAGE_W(2, 2); STAGE_X(2, 2);

#pragma unroll
    for (int kc = 0; kc < 12; kc++) {
        if (kc <= 9)       asm volatile("s_waitcnt vmcnt(10)" ::: "memory");
        else if (kc == 10) asm volatile("s_waitcnt vmcnt(5)" ::: "memory");
        else               asm volatile("s_waitcnt vmcnt(0)" ::: "memory");
        __builtin_amdgcn_s_barrier();         // chunk kc ready in all waves
        __builtin_amdgcn_sched_barrier(0);

        const int buf = kc % 3;
#pragma unroll
        for (int m = 0; m < 2; m++) {
            const int row = wr * 32 + m * 16 + lo;
            const int rg  = row & 7;
            float4 f00 = *reinterpret_cast<const float4*>(
                &xls[buf][row * 64 + (((2 * hi) ^ rg)) * 4]);
            float4 f01 = *reinterpret_cast<const float4*>(
                &xls[buf][row * 64 + (((2 * hi + 1) ^ rg)) * 4]);
            float4 f10 = *reinterpret_cast<const float4*>(
                &xls[buf][row * 64 + (8 + ((2 * hi) ^ rg)) * 4]);
            float4 f11 = *reinterpret_cast<const float4*>(
                &xls[buf][row * 64 + (8 + ((2 * hi + 1) ^ rg)) * 4]);
            short8 a0, a1;
#pragma unroll
            for (int e = 0; e < 4; e++) {
                a0[e]     = f2bf(f00[e]);
                a0[e + 4] = f2bf(f01[e]);
                a1[e]     = f2bf(f10[e]);
                a1[e + 4] = f2bf(f11[e]);
            }
#pragma unroll
            for (int j = 0; j < 3; j++) {
                const int brow = wc * 48 + j * 16 + lo;
                const int rx   = (brow & 7) << 3;
                short8 b0 = *reinterpret_cast<const short8*>(
                    &wtile[buf][brow * 64 + ((hi << 3) ^ rx)]);
                short8 b1 = *reinterpret_cast<const short8*>(
                    &wtile[buf][brow * 64 + (((hi + 4) << 3) ^ rx)]);
                acc[m * 3 + j] = __builtin_amdgcn_mfma_f32_16x16x32_bf16(a0, b0, acc[m * 3 + j], 0, 0, 0);
                acc[m * 3 + j] = __builtin_amdgcn_mfma_f32_16x16x32_bf16(a1, b1, acc[m * 3 + j], 0, 0, 0);
            }
        }
        __builtin_amdgcn_sched_barrier(0);
        __builtin_amdgcn_s_barrier();         // all waves done reading buf
        if (kc <= 8) {                        // refill buf with chunk kc+3
            STAGE_W(buf, kc + 3);
            STAGE_X(buf, kc + 3);
        }
    }
#undef STAGE_W
#undef STAGE_X

    // ---- epilogue ----
#pragma unroll
    for (int m = 0; m < 2; m++) {
        const int orow = row0 + wr * 32 + m * 16 + hi * 4;
#pragma unroll
        for (int j = 0; j < 3; j++) {
            const int cb = wc * 48 + j * 16;  // wave-uniform frag col base
            const f32x4 a = acc[m * 3 + j];
            if (cb < 64) {
#pragma unroll
                for (int r = 0; r < 4; r++)
                    qws[(size_t)(orow + r) * HS + cb + lo] = f2bf(a[r] * 0.125f);
            } else if (cb < 128) {
#pragma unroll
                for (int r = 0; r < 4; r++)
                    kws[(size_t)(orow + r) * HS + cb - 64 + lo] = f2bf(a[r]);
            } else {
                short4_ pv;
#pragma unroll
                for (int r = 0; r < 4; r++) pv[r] = f2bf(a[r]);
                *reinterpret_cast<short4_*>(
                    &vtg[((size_t)b * 64 + cb - 128 + lo) * T + t0 + wr * 32 + m * 16 + hi * 4]) = pv;
            }
        }
    }
}

// ---------------------------------------------------------------------------
// Kernel 2: causal flash attention (R20 P-path). SINGLE-buffered K/V with
// two barriers per iteration (LDS writes after post-PV barrier): LDS
// 40 -> 24 KB -> 6 blocks/CU capacity. S raised to 6 (grid 1536 = 6/CU).
// ---------------------------------------------------------------------------
__global__ __launch_bounds__(256, 6) void attn(const short* __restrict__ qg,
                                               const short* __restrict__ kg,
                                               const short* __restrict__ vtg,
                                               float* __restrict__ part, int S) {
    __shared__ short ks[64 * 64];             // 8 KB, single buffer
    __shared__ short vts[64 * 64];            // 8 KB, single buffer
    __shared__ short ps[4][16 * 64];          // 8 KB

    const int tid  = threadIdx.x;
    const int lane = tid & 63, w = tid >> 6;
    const int lo   = lane & 15, hi = lane >> 4;
    const int bid  = blockIdx.x;
    const int per_b = QT * S;
    const int b    = bid / per_b;
    const int r2   = bid % per_b;
    const int qt   = 31 - (r2 / S);           // heaviest-first
    const int c    = r2 % S;
    const int nkt  = qt + 1;
    const int base = nkt / S, rem = nkt % S;
    const int niter = base + (c < rem ? 1 : 0);
    const int kt0   = c * base + (c < rem ? c : rem);
    float* pout = part + (size_t)((b * QT + qt) * S + c) * PSTRIDE;

    float m_ = -1e30f;                        // per-lane state for q-row = lo
    f32x4 lac = f32x4{0.f, 0.f, 0.f, 0.f};    // 4-way partial l
    f32x4 oacc[4];
#pragma unroll
    for (int i = 0; i < 4; i++) oacc[i] = f32x4{0.f, 0.f, 0.f, 0.f};

    if (niter > 0) {
        const int qrow = qt * 64 + w * 16 + lo;
        const size_t qbase = ((size_t)b * T + qrow) * HS;
        short8 qa0 = *reinterpret_cast<const short8*>(&qg[qbase + hi * 8]);
        short8 qa1 = *reinterpret_cast<const short8*>(&qg[qbase + 32 + hi * 8]);

        const int srow = tid >> 2, scs = tid & 3, r7 = srow & 7;
        const int w0 = srow * 64 + (((scs * 2)     ^ r7) << 3);
        const int w1 = srow * 64 + (((scs * 2 + 1) ^ r7) << 3);
        const size_t kgoff = (size_t)b * T * HS;
        const size_t vgoff = ((size_t)b * 64 + srow) * T;

        short8 ka, kb2, va, vb;
        {
            const short* kp = &kg[kgoff + (size_t)(kt0 * 64 + srow) * HS + scs * 16];
            ka = *reinterpret_cast<const short8*>(kp);
            kb2 = *reinterpret_cast<const short8*>(kp + 8);
            const short* vp = &vtg[vgoff + kt0 * 64 + scs * 16];
            va = *reinterpret_cast<const short8*>(vp);
            vb = *reinterpret_cast<const short8*>(vp + 8);
        }
        *reinterpret_cast<short8*>(&ks[w0])  = ka;
        *reinterpret_cast<short8*>(&ks[w1])  = kb2;
        *reinterpret_cast<short8*>(&vts[w0]) = va;
        *reinterpret_cast<short8*>(&vts[w1]) = vb;

        const int pswz = (lo & 7) << 3;       // P swizzle for this lane's row
        for (int i = 0; i < niter; i++) {
            const int kt = kt0 + i;
            if (i + 1 < niter) {              // prefetch next tile -> regs
                const short* kp = &kg[kgoff + (size_t)((kt + 1) * 64 + srow) * HS + scs * 16];
                ka = *reinterpret_cast<const short8*>(kp);
                kb2 = *reinterpret_cast<const short8*>(kp + 8);
                const short* vp = &vtg[vgoff + (kt + 1) * 64 + scs * 16];
                va = *reinterpret_cast<const short8*>(vp);
                vb = *reinterpret_cast<const short8*>(vp + 8);
            }
            __syncthreads();                  // K/V tile fully written

            // ---- S^T = K Q^T (swapped): sacc[nt][r] = S[key=nt*16+hi*4+r][q=lo]
            f32x4 sacc[4];
#pragma unroll
            for (int nt = 0; nt < 4; nt++) sacc[nt] = f32x4{0.f, 0.f, 0.f, 0.f};
            __builtin_amdgcn_s_setprio(1);
#pragma unroll
            for (int nt = 0; nt < 4; nt++) {
                const int row = nt * 16 + lo, rr = row & 7;
                short8 b0 = *reinterpret_cast<const short8*>(
                    &ks[row * 64 + ((hi ^ rr) << 3)]);
                short8 b1 = *reinterpret_cast<const short8*>(
                    &ks[row * 64 + (((hi + 4) ^ rr) << 3)]);
                sacc[nt] = __builtin_amdgcn_mfma_f32_16x16x32_bf16(b0, qa0, sacc[nt], 0, 0, 0);
                sacc[nt] = __builtin_amdgcn_mfma_f32_16x16x32_bf16(b1, qa1, sacc[nt], 0, 0, 0);
            }
            __builtin_amdgcn_s_setprio(0);

            if (kt == qt) {                   // causal: key > qrow -> -inf
#pragma unroll
                for (int nt = 0; nt < 4; nt++)
#pragma unroll
                    for (int r = 0; r < 4; r++)
                        if (nt * 16 + hi * 4 + r > w * 16 + lo) sacc[nt][r] = -1e30f;
            }

            // ---- online softmax: in-register tree + 2 shuffles ----
            float tm = fmaxf(fmaxf(fmaxf(sacc[0][0], sacc[0][1]), fmaxf(sacc[0][2], sacc[0][3])),
                             fmaxf(fmaxf(sacc[1][0], sacc[1][1]), fmaxf(sacc[1][2], sacc[1][3])));
            tm = fmaxf(tm, fmaxf(fmaxf(fmaxf(sacc[2][0], sacc[2][1]), fmaxf(sacc[2][2], sacc[2][3])),
                                 fmaxf(fmaxf(sacc[3][0], sacc[3][1]), fmaxf(sacc[3][2], sacc[3][3]))));
            tm = fmaxf(tm, __shfl_xor(tm, 16));
            tm = fmaxf(tm, __shfl_xor(tm, 32));

            if (!__all(tm <= m_ + 8.0f)) {    // defer-max: rescale rarely
                float mnew = fmaxf(m_, tm);
                float corr = __expf(m_ - mnew);
#pragma unroll
                for (int r = 0; r < 4; r++) lac[r] *= corr;
#pragma unroll
                for (int r = 0; r < 4; r++) {
                    float cr = __shfl(corr, (lane & 48) | (hi * 4 + r));
#pragma unroll
                    for (int nt = 0; nt < 4; nt++) oacc[nt][r] *= cr;
                }
                m_ = mnew;
            }

            // ---- P = exp(S-m), partial l, f2bf-packed short4_ -> ps (8B) ----
#pragma unroll
            for (int nt = 0; nt < 4; nt++) {
                float p0 = __expf(sacc[nt][0] - m_);
                float p1 = __expf(sacc[nt][1] - m_);
                float p2 = __expf(sacc[nt][2] - m_);
                float p3 = __expf(sacc[nt][3] - m_);
                lac[0] += p0; lac[1] += p1; lac[2] += p2; lac[3] += p3;
                short4_ pk;
                pk[0] = f2bf(p0); pk[1] = f2bf(p1);
                pk[2] = f2bf(p2); pk[3] = f2bf(p3);
                *reinterpret_cast<short4_*>(
                    &ps[w][lo * 64 + ((nt * 16 + hi * 4) ^ pswz)]) = pk;
            }
            asm volatile("" ::: "memory");    // order P stores before PV loads

            // ---- O += P V ----
            short8 pa0 = *reinterpret_cast<const short8*>(
                &ps[w][lo * 64 + ((hi << 3) ^ pswz)]);
            short8 pa1 = *reinterpret_cast<const short8*>(
                &ps[w][lo * 64 + (((hi + 4) << 3) ^ pswz)]);
            __builtin_amdgcn_s_setprio(1);
#pragma unroll
            for (int nt = 0; nt < 4; nt++) {
                const int row = nt * 16 + lo, rr = row & 7;
                short8 b0 = *reinterpret_cast<const short8*>(
                    &vts[row * 64 + ((hi ^ rr) << 3)]);
                short8 b1 = *reinterpret_cast<const short8*>(
                    &vts[row * 64 + (((hi + 4) ^ rr) << 3)]);
                oacc[nt] = __builtin_amdgcn_mfma_f32_16x16x32_bf16(pa0, b0, oacc[nt], 0, 0, 0);
                oacc[nt] = __builtin_amdgcn_mfma_f32_16x16x32_bf16(pa1, b1, oacc[nt], 0, 0, 0);
            }
            __builtin_amdgcn_s_setprio(0);

            __syncthreads();                  // all waves done reading K/V
            if (i + 1 < niter) {              // overwrite single buffers
                *reinterpret_cast<short8*>(&ks[w0])  = ka;
                *reinterpret_cast<short8*>(&ks[w1])  = kb2;
                *reinterpret_cast<short8*>(&vts[w0]) = va;
                *reinterpret_cast<short8*>(&vts[w1]) = vb;
            }
        }
    }

    // ---- epilogue: fold partials; reduce l across hi; redistribute ----
    float l_ = (lac[0] + lac[1]) + (lac[2] + lac[3]);
    float lt = l_;
    lt += __shfl_xor(lt, 16);
    lt += __shfl_xor(lt, 32);

#pragma unroll
    for (int nt = 0; nt < 4; nt++)
#pragma unroll
        for (int r = 0; r < 4; r++)
            pout[(w * 16 + hi * 4 + r) * 64 + nt * 16 + lo] = oacc[nt][r];
    float mfor[4], lfor[4];
#pragma unroll
    for (int r = 0; r < 4; r++) {
        mfor[r] = __shfl(m_, (lane & 48) | (hi * 4 + r));
        lfor[r] = __shfl(lt, (lane & 48) | (hi * 4 + r));
    }
    if (lo == 0) {
#pragma unroll
        for (int r = 0; r < 4; r++) {
            const int row = w * 16 + hi * 4 + r;
            pout[4096 + row] = mfor[r];
            pout[4160 + row] = lfor[r];
        }
    }
}

// ---------------------------------------------------------------------------
// Kernel 3: combine the S partials -> normalized fp32 output (S up to 8).
// ---------------------------------------------------------------------------
__global__ __launch_bounds__(256) void combine(const float* __restrict__ part,
                                               float* __restrict__ out, int S) {
    const int bid = blockIdx.x;               // b*32 + qt
    const int b = bid >> 5, qt = bid & 31;
    const float* p = part + (size_t)bid * S * PSTRIDE;
    const int row = threadIdx.x >> 2, cs = threadIdx.x & 3;

    float mv[8], lv[8], av[8];
    float M = -1e30f;
    for (int s = 0; s < S; s++) {
        mv[s] = p[(size_t)s * PSTRIDE + 4096 + row];
        lv[s] = p[(size_t)s * PSTRIDE + 4160 + row];
        M = fmaxf(M, mv[s]);
    }
    float den = 0.0f;
    for (int s = 0; s < S; s++) { av[s] = __expf(mv[s] - M); den += lv[s] * av[s]; }
    float inv = 1.0f / den;

    float* o = out + ((size_t)b * T + qt * 64 + row) * HS + cs * 16;
#pragma unroll
    for (int i = 0; i < 4; i++) {
        float4 res = make_float4(0.f, 0.f, 0.f, 0.f);
        for (int s = 0; s < S; s++) {
            float4 v = *reinterpret_cast<const float4*>(
                p + (size_t)s * PSTRIDE + row * 64 + cs * 16 + i * 4);
            res.x += v.x * av[s]; res.y += v.y * av[s];
            res.z += v.z * av[s]; res.w += v.w * av[s];
        }
        res.x *= inv; res.y *= inv; res.z *= inv; res.w *= inv;
        *reinterpret_cast<float4*>(o + i * 4) = res;
    }
}

// ---------------------------------------------------------------------------
extern "C" void kernel_launch(void* const* d_in, const int* in_sizes, int n_in,
                              void* d_out, int out_size, void* d_ws, size_t ws_size,
                              hipStream_t stream) {
    const float* x  = (const float*)d_in[0];
    const float* Wq = (const float*)d_in[1];
    const float* Wk = (const float*)d_in[2];
    const float* Wv = (const float*)d_in[3];
    float* out = (float*)d_out;

    short* ws   = (short*)d_ws;
    short* qws  = ws;
    short* kws  = qws + (size_t)BT * HS;
    short* vtws = kws + (size_t)BT * HS;
    short* Wt   = vtws + (size_t)BT * HS;
    float* part = (float*)(Wt + (size_t)192 * D);

    const size_t fixed = (size_t)3 * BT * HS * 2 + (size_t)192 * D * 2;
    int S = 6;
    while (S > 1 && fixed + (size_t)Bb * QT * S * PSTRIDE * 4 > ws_size) S--;

    wt_kernel<<<192, 256, 0, stream>>>(Wq, Wk, Wv, Wt);
    qkv_proj<<<BT / 64, 512, 0, stream>>>(x, Wt, qws, kws, vtws);
    attn<<<Bb * QT * S, 256, 0, stream>>>(qws, kws, vtws, part, S);
    combine<<<Bb * QT, 256, 0, stream>>>(part, out, S);
}

// Round 26
// 52.416 us; speedup vs baseline: 1.3323x; 1.3323x over previous
//
#include <hip/hip_runtime.h>

typedef float  f32x4  __attribute__((ext_vector_type(4)));
typedef short  short8 __attribute__((ext_vector_type(8)));
typedef short  short4_ __attribute__((ext_vector_type(4)));

constexpr int Bb = 8, T = 2048, D = 768, HS = 64;
constexpr int BT = Bb * T;
constexpr int QT = T / 64;              // 32 q-tiles per batch
constexpr int PSTRIDE = 64 * 64 + 128;  // floats per partial (O' + m + l)

__device__ __forceinline__ short f2bf(float f) {
    unsigned u = __builtin_bit_cast(unsigned, f);
    unsigned r = (u + 0x7FFFu + ((u >> 16) & 1u)) >> 16;
    return (short)r;
}

__device__ __forceinline__ void gld_lds16(const void* g, void* l) {
    __builtin_amdgcn_global_load_lds(
        (const __attribute__((address_space(1))) unsigned int*)g,
        (__attribute__((address_space(3))) unsigned int*)l, 16, 0, 0);
}

// ---------------------------------------------------------------------------
// Kernel 0: transpose Wq|Wk|Wv (fp32 [768][64] each) -> Wt bf16 [192][768]
// ---------------------------------------------------------------------------
__global__ __launch_bounds__(256) void wt_kernel(const float* __restrict__ Wq,
                                                 const float* __restrict__ Wk,
                                                 const float* __restrict__ Wv,
                                                 short* __restrict__ Wt) {
    int n = blockIdx.x;                       // 0..191 composite output col
    const float* W = (n < 64) ? Wq : (n < 128) ? Wk : Wv;
    int c = n & 63;
    for (int kk = threadIdx.x; kk < D; kk += 256)
        Wt[n * D + kk] = f2bf(W[kk * HS + c]);
}

// ---------------------------------------------------------------------------
// Kernel 1: QKV projection (R14 pipelined structure, ~11.5 us measured R16).
// ---------------------------------------------------------------------------
__global__ __launch_bounds__(512) void qkv_proj(const float* __restrict__ x,
                                                const short* __restrict__ Wt,
                                                short* __restrict__ qws,
                                                short* __restrict__ kws,
                                                short* __restrict__ vtg) {
    __shared__ alignas(16) short wtile[3][192 * 64]; // 72 KB bf16
    __shared__ alignas(16) float xls[3][64 * 64];    // 48 KB fp32

    const int tid  = threadIdx.x;             // 0..511
    const int lane = tid & 63, w = tid >> 6;
    const int lo   = lane & 15, hi = lane >> 4;
    const int wr   = w >> 2, wc = w & 3;      // wave row (2) x col (4)
    const int row0 = blockIdx.x * 64;
    const int b    = row0 >> 11, t0 = row0 & 2047;

    f32x4 acc[6];
#pragma unroll
    for (int j = 0; j < 6; j++) acc[j] = f32x4{0.f, 0.f, 0.f, 0.f};

#define STAGE_W(bufi, kc)                                                      \
    {                                                                          \
        _Pragma("unroll")                                                      \
        for (int it = 0; it < 3; it++) {                                       \
            int ci = it * 512 + w * 64 + lane;                                 \
            int n = ci >> 3, seg = ci & 7;                                     \
            gld_lds16(&Wt[(size_t)n * D + (kc) * 64 + ((seg ^ (n & 7)) << 3)], \
                      &wtile[bufi][(it * 512 + w * 64) * 8]);                  \
        }                                                                      \
    }
#define STAGE_X(bufi, kc)                                                      \
    {                                                                          \
        _Pragma("unroll")                                                      \
        for (int it = 0; it < 2; it++) {                                       \
            int idx = it * 512 + tid;                                          \
            int row = idx >> 4, g = idx & 15;                                  \
            int sg = (g & 8) | ((g & 7) ^ (row & 7));                          \
            gld_lds16(&x[(size_t)(row0 + row) * D + (kc) * 64 + sg * 4],       \
                      &xls[bufi][(it * 512 + w * 64) * 4]);                    \
        }                                                                      \
    }

    STAGE_W(0, 0); STAGE_X(0, 0);
    STAGE_W(1, 1); STAGE_X(1, 1);
    STAGE_W(2, 2); STAGE_X(2, 2);

#pragma unroll
    for (int kc = 0; kc < 12; kc++) {
        if (kc <= 9)       asm volatile("s_waitcnt vmcnt(10)" ::: "memory");
        else if (kc == 10) asm volatile("s_waitcnt vmcnt(5)" ::: "memory");
        else               asm volatile("s_waitcnt vmcnt(0)" ::: "memory");
        __builtin_amdgcn_s_barrier();         // chunk kc ready in all waves
        __builtin_amdgcn_sched_barrier(0);

        const int buf = kc % 3;
#pragma unroll
        for (int m = 0; m < 2; m++) {
            const int row = wr * 32 + m * 16 + lo;
            const int rg  = row & 7;
            float4 f00 = *reinterpret_cast<const float4*>(
                &xls[buf][row * 64 + (((2 * hi) ^ rg)) * 4]);
            float4 f01 = *reinterpret_cast<const float4*>(
                &xls[buf][row * 64 + (((2 * hi + 1) ^ rg)) * 4]);
            float4 f10 = *reinterpret_cast<const float4*>(
                &xls[buf][row * 64 + (8 + ((2 * hi) ^ rg)) * 4]);
            float4 f11 = *reinterpret_cast<const float4*>(
                &xls[buf][row * 64 + (8 + ((2 * hi + 1) ^ rg)) * 4]);
            short8 a0, a1;
#pragma unroll
            for (int e = 0; e < 4; e++) {
                a0[e]     = f2bf(f00[e]);
                a0[e + 4] = f2bf(f01[e]);
                a1[e]     = f2bf(f10[e]);
                a1[e + 4] = f2bf(f11[e]);
            }
#pragma unroll
            for (int j = 0; j < 3; j++) {
                const int brow = wc * 48 + j * 16 + lo;
                const int rx   = (brow & 7) << 3;
                short8 b0 = *reinterpret_cast<const short8*>(
                    &wtile[buf][brow * 64 + ((hi << 3) ^ rx)]);
                short8 b1 = *reinterpret_cast<const short8*>(
                    &wtile[buf][brow * 64 + (((hi + 4) << 3) ^ rx)]);
                acc[m * 3 + j] = __builtin_amdgcn_mfma_f32_16x16x32_bf16(a0, b0, acc[m * 3 + j], 0, 0, 0);
                acc[m * 3 + j] = __builtin_amdgcn_mfma_f32_16x16x32_bf16(a1, b1, acc[m * 3 + j], 0, 0, 0);
            }
        }
        __builtin_amdgcn_sched_barrier(0);
        __builtin_amdgcn_s_barrier();         // all waves done reading buf
        if (kc <= 8) {                        // refill buf with chunk kc+3
            STAGE_W(buf, kc + 3);
            STAGE_X(buf, kc + 3);
        }
    }
#undef STAGE_W
#undef STAGE_X

    // ---- epilogue ----
#pragma unroll
    for (int m = 0; m < 2; m++) {
        const int orow = row0 + wr * 32 + m * 16 + hi * 4;
#pragma unroll
        for (int j = 0; j < 3; j++) {
            const int cb = wc * 48 + j * 16;  // wave-uniform frag col base
            const f32x4 a = acc[m * 3 + j];
            if (cb < 64) {
#pragma unroll
                for (int r = 0; r < 4; r++)
                    qws[(size_t)(orow + r) * HS + cb + lo] = f2bf(a[r] * 0.125f);
            } else if (cb < 128) {
#pragma unroll
                for (int r = 0; r < 4; r++)
                    kws[(size_t)(orow + r) * HS + cb - 64 + lo] = f2bf(a[r]);
            } else {
                short4_ pv;
#pragma unroll
                for (int r = 0; r < 4; r++) pv[r] = f2bf(a[r]);
                *reinterpret_cast<short4_*>(
                    &vtg[((size_t)b * 64 + cb - 128 + lo) * T + t0 + wr * 32 + m * 16 + hi * 4]) = pv;
            }
        }
    }
}

// ---------------------------------------------------------------------------
// Kernel 2: causal flash attention (swapped QK^T, S=4). P-path: scalar f2bf
// packed into ONE short4_ 8-byte LDS store per nt; l as 4 partials.
// Exact R20 structure (measured 52.9 us total).
// ---------------------------------------------------------------------------
__global__ __launch_bounds__(256, 4) void attn(const short* __restrict__ qg,
                                               const short* __restrict__ kg,
                                               const short* __restrict__ vtg,
                                               float* __restrict__ part, int S) {
    __shared__ short ks[2][64 * 64];
    __shared__ short vts[2][64 * 64];
    __shared__ short ps[4][16 * 64];

    const int tid  = threadIdx.x;
    const int lane = tid & 63, w = tid >> 6;
    const int lo   = lane & 15, hi = lane >> 4;
    const int bid  = blockIdx.x;
    const int per_b = QT * S;
    const int b    = bid / per_b;
    const int r2   = bid % per_b;
    const int qt   = 31 - (r2 / S);           // heaviest-first
    const int c    = r2 % S;
    const int nkt  = qt + 1;
    const int base = nkt / S, rem = nkt % S;
    const int niter = base + (c < rem ? 1 : 0);
    const int kt0   = c * base + (c < rem ? c : rem);
    float* pout = part + (size_t)((b * QT + qt) * S + c) * PSTRIDE;

    float m_ = -1e30f;                        // per-lane state for q-row = lo
    f32x4 lac = f32x4{0.f, 0.f, 0.f, 0.f};    // 4-way partial l
    f32x4 oacc[4];
#pragma unroll
    for (int i = 0; i < 4; i++) oacc[i] = f32x4{0.f, 0.f, 0.f, 0.f};

    if (niter > 0) {
        const int qrow = qt * 64 + w * 16 + lo;
        const size_t qbase = ((size_t)b * T + qrow) * HS;
        short8 qa0 = *reinterpret_cast<const short8*>(&qg[qbase + hi * 8]);
        short8 qa1 = *reinterpret_cast<const short8*>(&qg[qbase + 32 + hi * 8]);

        const int srow = tid >> 2, scs = tid & 3, r7 = srow & 7;
        const int w0 = srow * 64 + (((scs * 2)     ^ r7) << 3);
        const int w1 = srow * 64 + (((scs * 2 + 1) ^ r7) << 3);
        const size_t kgoff = (size_t)b * T * HS;
        const size_t vgoff = ((size_t)b * 64 + srow) * T;

        short8 ka, kb2, va, vb;
        {
            const short* kp = &kg[kgoff + (size_t)(kt0 * 64 + srow) * HS + scs * 16];
            ka = *reinterpret_cast<const short8*>(kp);
            kb2 = *reinterpret_cast<const short8*>(kp + 8);
            const short* vp = &vtg[vgoff + kt0 * 64 + scs * 16];
            va = *reinterpret_cast<const short8*>(vp);
            vb = *reinterpret_cast<const short8*>(vp + 8);
        }
        *reinterpret_cast<short8*>(&ks[0][w0])  = ka;
        *reinterpret_cast<short8*>(&ks[0][w1])  = kb2;
        *reinterpret_cast<short8*>(&vts[0][w0]) = va;
        *reinterpret_cast<short8*>(&vts[0][w1]) = vb;

        const int pswz = (lo & 7) << 3;       // P swizzle for this lane's row
        int cur = 0;
        for (int i = 0; i < niter; i++) {
            const int kt = kt0 + i;
            if (i + 1 < niter) {              // prefetch next tile -> regs
                const short* kp = &kg[kgoff + (size_t)((kt + 1) * 64 + srow) * HS + scs * 16];
                ka = *reinterpret_cast<const short8*>(kp);
                kb2 = *reinterpret_cast<const short8*>(kp + 8);
                const short* vp = &vtg[vgoff + (kt + 1) * 64 + scs * 16];
                va = *reinterpret_cast<const short8*>(vp);
                vb = *reinterpret_cast<const short8*>(vp + 8);
            }
            __syncthreads();                  // buf[cur] ready

            // ---- S^T = K Q^T (swapped): sacc[nt][r] = S[key=nt*16+hi*4+r][q=lo]
            f32x4 sacc[4];
#pragma unroll
            for (int nt = 0; nt < 4; nt++) sacc[nt] = f32x4{0.f, 0.f, 0.f, 0.f};
            __builtin_amdgcn_s_setprio(1);
#pragma unroll
            for (int nt = 0; nt < 4; nt++) {
                const int row = nt * 16 + lo, rr = row & 7;
                short8 b0 = *reinterpret_cast<const short8*>(
                    &ks[cur][row * 64 + ((hi ^ rr) << 3)]);
                short8 b1 = *reinterpret_cast<const short8*>(
                    &ks[cur][row * 64 + (((hi + 4) ^ rr) << 3)]);
                sacc[nt] = __builtin_amdgcn_mfma_f32_16x16x32_bf16(b0, qa0, sacc[nt], 0, 0, 0);
                sacc[nt] = __builtin_amdgcn_mfma_f32_16x16x32_bf16(b1, qa1, sacc[nt], 0, 0, 0);
            }
            __builtin_amdgcn_s_setprio(0);

            if (kt == qt) {                   // causal: key > qrow -> -inf
#pragma unroll
                for (int nt = 0; nt < 4; nt++)
#pragma unroll
                    for (int r = 0; r < 4; r++)
                        if (nt * 16 + hi * 4 + r > w * 16 + lo) sacc[nt][r] = -1e30f;
            }

            // ---- online softmax: in-register tree + 2 shuffles ----
            float tm = fmaxf(fmaxf(fmaxf(sacc[0][0], sacc[0][1]), fmaxf(sacc[0][2], sacc[0][3])),
                             fmaxf(fmaxf(sacc[1][0], sacc[1][1]), fmaxf(sacc[1][2], sacc[1][3])));
            tm = fmaxf(tm, fmaxf(fmaxf(fmaxf(sacc[2][0], sacc[2][1]), fmaxf(sacc[2][2], sacc[2][3])),
                                 fmaxf(fmaxf(sacc[3][0], sacc[3][1]), fmaxf(sacc[3][2], sacc[3][3]))));
            tm = fmaxf(tm, __shfl_xor(tm, 16));
            tm = fmaxf(tm, __shfl_xor(tm, 32));

            if (!__all(tm <= m_ + 8.0f)) {    // defer-max: rescale rarely
                float mnew = fmaxf(m_, tm);
                float corr = __expf(m_ - mnew);
#pragma unroll
                for (int r = 0; r < 4; r++) lac[r] *= corr;
#pragma unroll
                for (int r = 0; r < 4; r++) {
                    float cr = __shfl(corr, (lane & 48) | (hi * 4 + r));
#pragma unroll
                    for (int nt = 0; nt < 4; nt++) oacc[nt][r] *= cr;
                }
                m_ = mnew;
            }

            // ---- P = exp(S-m), partial l, f2bf-packed short4_ -> ps (8B) ----
#pragma unroll
            for (int nt = 0; nt < 4; nt++) {
                float p0 = __expf(sacc[nt][0] - m_);
                float p1 = __expf(sacc[nt][1] - m_);
                float p2 = __expf(sacc[nt][2] - m_);
                float p3 = __expf(sacc[nt][3] - m_);
                lac[0] += p0; lac[1] += p1; lac[2] += p2; lac[3] += p3;
                short4_ pk;
                pk[0] = f2bf(p0); pk[1] = f2bf(p1);
                pk[2] = f2bf(p2); pk[3] = f2bf(p3);
                *reinterpret_cast<short4_*>(
                    &ps[w][lo * 64 + ((nt * 16 + hi * 4) ^ pswz)]) = pk;
            }
            asm volatile("" ::: "memory");    // order P stores before PV loads

            // ---- O += P V ----
            short8 pa0 = *reinterpret_cast<const short8*>(
                &ps[w][lo * 64 + ((hi << 3) ^ pswz)]);
            short8 pa1 = *reinterpret_cast<const short8*>(
                &ps[w][lo * 64 + (((hi + 4) << 3) ^ pswz)]);
            __builtin_amdgcn_s_setprio(1);
#pragma unroll
            for (int nt = 0; nt < 4; nt++) {
                const int row = nt * 16 + lo, rr = row & 7;
                short8 b0 = *reinterpret_cast<const short8*>(
                    &vts[cur][row * 64 + ((hi ^ rr) << 3)]);
                short8 b1 = *reinterpret_cast<const short8*>(
                    &vts[cur][row * 64 + (((hi + 4) ^ rr) << 3)]);
                oacc[nt] = __builtin_amdgcn_mfma_f32_16x16x32_bf16(pa0, b0, oacc[nt], 0, 0, 0);
                oacc[nt] = __builtin_amdgcn_mfma_f32_16x16x32_bf16(pa1, b1, oacc[nt], 0, 0, 0);
            }
            __builtin_amdgcn_s_setprio(0);

            if (i + 1 < niter) {              // write prefetched tile
                *reinterpret_cast<short8*>(&ks[cur ^ 1][w0])  = ka;
                *reinterpret_cast<short8*>(&ks[cur ^ 1][w1])  = kb2;
                *reinterpret_cast<short8*>(&vts[cur ^ 1][w0]) = va;
                *reinterpret_cast<short8*>(&vts[cur ^ 1][w1]) = vb;
            }
            cur ^= 1;
        }
    }

    // ---- epilogue: fold partials; reduce l across hi; redistribute ----
    float l_ = (lac[0] + lac[1]) + (lac[2] + lac[3]);
    float lt = l_;
    lt += __shfl_xor(lt, 16);
    lt += __shfl_xor(lt, 32);

#pragma unroll
    for (int nt = 0; nt < 4; nt++)
#pragma unroll
        for (int r = 0; r < 4; r++)
            pout[(w * 16 + hi * 4 + r) * 64 + nt * 16 + lo] = oacc[nt][r];
    float mfor[4], lfor[4];
#pragma unroll
    for (int r = 0; r < 4; r++) {
        mfor[r] = __shfl(m_, (lane & 48) | (hi * 4 + r));
        lfor[r] = __shfl(lt, (lane & 48) | (hi * 4 + r));
    }
    if (lo == 0) {
#pragma unroll
        for (int r = 0; r < 4; r++) {
            const int row = w * 16 + hi * 4 + r;
            pout[4096 + row] = mfor[r];
            pout[4160 + row] = lfor[r];
        }
    }
}

// ---------------------------------------------------------------------------
// Kernel 3: combine the S partials -> normalized fp32 output.
// ---------------------------------------------------------------------------
__global__ __launch_bounds__(256) void combine(const float* __restrict__ part,
                                               float* __restrict__ out, int S) {
    const int bid = blockIdx.x;               // b*32 + qt
    const int b = bid >> 5, qt = bid & 31;
    const float* p = part + (size_t)bid * S * PSTRIDE;
    const int row = threadIdx.x >> 2, cs = threadIdx.x & 3;

    float mv[4], lv[4], av[4];
    float M = -1e30f;
    for (int s = 0; s < S; s++) {
        mv[s] = p[(size_t)s * PSTRIDE + 4096 + row];
        lv[s] = p[(size_t)s * PSTRIDE + 4160 + row];
        M = fmaxf(M, mv[s]);
    }
    float den = 0.0f;
    for (int s = 0; s < S; s++) { av[s] = __expf(mv[s] - M); den += lv[s] * av[s]; }
    float inv = 1.0f / den;

    float* o = out + ((size_t)b * T + qt * 64 + row) * HS + cs * 16;
#pragma unroll
    for (int i = 0; i < 4; i++) {
        float4 res = make_float4(0.f, 0.f, 0.f, 0.f);
        for (int s = 0; s < S; s++) {
            float4 v = *reinterpret_cast<const float4*>(
                p + (size_t)s * PSTRIDE + row * 64 + cs * 16 + i * 4);
            res.x += v.x * av[s]; res.y += v.y * av[s];
            res.z += v.z * av[s]; res.w += v.w * av[s];
        }
        res.x *= inv; res.y *= inv; res.z *= inv; res.w *= inv;
        *reinterpret_cast<float4*>(o + i * 4) = res;
    }
}

// ---------------------------------------------------------------------------
extern "C" void kernel_launch(void* const* d_in, const int* in_sizes, int n_in,
                              void* d_out, int out_size, void* d_ws, size_t ws_size,
                              hipStream_t stream) {
    const float* x  = (const float*)d_in[0];
    const float* Wq = (const float*)d_in[1];
    const float* Wk = (const float*)d_in[2];
    const float* Wv = (const float*)d_in[3];
    float* out = (float*)d_out;

    short* ws   = (short*)d_ws;
    short* qws  = ws;
    short* kws  = qws + (size_t)BT * HS;
    short* vtws = kws + (size_t)BT * HS;
    short* Wt   = vtws + (size_t)BT * HS;
    float* part = (float*)(Wt + (size_t)192 * D);

    const size_t fixed = (size_t)3 * BT * HS * 2 + (size_t)192 * D * 2;
    int S = 4;
    while (S > 1 && fixed + (size_t)Bb * QT * S * PSTRIDE * 4 > ws_size) S >>= 1;

    wt_kernel<<<192, 256, 0, stream>>>(Wq, Wk, Wv, Wt);
    qkv_proj<<<BT / 64, 512, 0, stream>>>(x, Wt, qws, kws, vtws);
    attn<<<Bb * QT * S, 256, 0, stream>>>(qws, kws, vtws, part, S);
    combine<<<Bb * QT, 256, 0, stream>>>(part, out, S);
}